// Round 11
// baseline (396.921 us; speedup 1.0000x reference)
//
#include <hip/hip_runtime.h>
#include <hip/hip_bf16.h>

#define N_NODES 50000
#define N_EDGES 600000
#define NMETA   3
#define LTOT (NMETA * N_NODES)          // 150000
#define SPAN_SHIFT 9
#define NBUCK 98                         // ceil(50000 / 512)
#define BCAP 8192
#define NCHUNK 147                       // ceil(600000 / 4096)
#define NABLK 782                        // ceil(50000 / 64) alpha blocks
#define LOG2E 1.4426950408889634f

typedef unsigned short u16;
typedef short bf16x8 __attribute__((ext_vector_type(8)));
typedef float f32x4 __attribute__((ext_vector_type(4)));

__device__ __forceinline__ float bf2f(u16 v) {
    union { unsigned int u; float f; } x; x.u = ((unsigned int)v) << 16; return x.f;
}
__device__ __forceinline__ float u2f(unsigned int u) {
    union { unsigned int u; float f; } x; x.u = u; return x.f;
}
__device__ __forceinline__ u16 f2bf(float f) {
    return __hip_bfloat16_raw(__float2bfloat16(f)).x;
}

// ---- build1: csrA (0..440) || prep_w (441..696) || alpha via va-trick (697..1478) ----
__global__ __launch_bounds__(256) void k_build1(
    const int* __restrict__ ei, int* __restrict__ gcnt,
    unsigned long long* __restrict__ pairs,
    const float* __restrict__ W, const float* __restrict__ W1,
    u16* __restrict__ WT, u16* __restrict__ W1T,
    const float* __restrict__ x,
    const float* __restrict__ att_src, const float* __restrict__ att_dst,
    float* __restrict__ alpha_s, float* __restrict__ alpha_d)
{
    const int bid = blockIdx.x;
    const int t = threadIdx.x;
    if (bid >= NMETA * NCHUNK + 256) {
        // ---- alpha branch: alpha[v][n][h] = x[n] . va[v][:,h]  (x LOG2E) ----
        __shared__ float va[6][128][4];      // [v][k][h]
        __shared__ float xl[64][129];
        const int row0 = (bid - (NMETA * NCHUNK + 256)) * 64;
        for (int idx = t; idx < 3072; idx += 256) {
            int v = idx >> 9, r = idx & 511, k = r >> 2, hh = r & 3;
            int m = v >> 1;
            const float* att = ((v & 1) ? att_dst : att_src) + m * 128 + hh * 32;
            const float* wp = W + (size_t)m * 16384 + k * 128 + hh * 32;
            float s = 0.f;
            #pragma unroll
            for (int d = 0; d < 32; ++d) s += wp[d] * att[d];
            va[v][k][hh] = s * LOG2E;
        }
        for (int i = t; i < 64 * 32; i += 256) {
            int r = i >> 5, q = i & 31;
            int n = row0 + r;
            float4 vx = make_float4(0.f, 0.f, 0.f, 0.f);
            if (n < N_NODES) vx = ((const float4*)(x + (size_t)n * 128))[q];
            xl[r][q * 4 + 0] = vx.x; xl[r][q * 4 + 1] = vx.y;
            xl[r][q * 4 + 2] = vx.z; xl[r][q * 4 + 3] = vx.w;
        }
        __syncthreads();
        const int r = t & 63;
        const int n = row0 + r;
        for (int v = t >> 6; v < 6; v += 4) {
            float a0 = 0.f, a1 = 0.f, a2 = 0.f, a3 = 0.f;
            for (int k = 0; k < 128; ++k) {
                float xk = xl[r][k];
                float4 vv = *(const float4*)&va[v][k][0];
                a0 += xk * vv.x; a1 += xk * vv.y; a2 += xk * vv.z; a3 += xk * vv.w;
            }
            if (n < N_NODES) {
                int m = v >> 1;
                float* dst = ((v & 1) ? alpha_d : alpha_s) + ((size_t)m * N_NODES + n) * 4;
                f32x4 o = {a0, a1, a2, a3};
                *(f32x4*)dst = o;
            }
        }
        return;
    }
    if (bid >= NMETA * NCHUNK) {
        // ---- prep_w ----
        int idx = (bid - NMETA * NCHUNK) * 256 + t;
        if (idx < NMETA * 16384) {
            int m = idx >> 14, r = idx & 16383;
            int col = r >> 7, k = r & 127;
            WT[idx] = f2bf(W[(m << 14) + k * 128 + col]);
        } else {
            int r = idx - NMETA * 16384;
            int col = r >> 7, k = r & 127;
            W1T[r] = f2bf(W1[k * 128 + col]);
        }
        return;
    }
    // ---- csrA ----
    const int m = bid / NCHUNK;
    const int e0 = (bid % NCHUNK) * 4096;
    __shared__ int cnt[NBUCK];
    __shared__ int gbase[NBUCK];
    if (t < NBUCK) cnt[t] = 0;
    __syncthreads();
    const int* srcp = ei + (size_t)m * 2 * N_EDGES;
    const int* dstp = srcp + N_EDGES;
    int sa[16], da[16], sl[16];
    #pragma unroll
    for (int j = 0; j < 16; ++j) {
        int e = e0 + j * 256 + t;
        if (e < N_EDGES) {
            int s = srcp[e], d = dstp[e];
            if ((unsigned)s >= N_NODES) s = 0;
            if ((unsigned)d >= N_NODES) d = 0;
            sa[j] = s; da[j] = d;
            sl[j] = atomicAdd(&cnt[d >> SPAN_SHIFT], 1);
        } else sl[j] = -1;
    }
    __syncthreads();
    if (t < NBUCK) gbase[t] = atomicAdd(&gcnt[m * NBUCK + t], cnt[t]);
    __syncthreads();
    #pragma unroll
    for (int j = 0; j < 16; ++j) {
        if (sl[j] < 0) continue;
        int b = da[j] >> SPAN_SHIFT;
        int pos = gbase[b] + sl[j];
        if (pos < BCAP)
            pairs[(size_t)(m * NBUCK + b) * BCAP + pos] =
                ((unsigned long long)(da[j] & 511) << 32) | (unsigned)(sa[j] * 128);
    }
}

// ---- build2: csrB+ew (0..293) || gemm_h (294..2639) ----
__global__ __launch_bounds__(256) void k_build2(
    const int* __restrict__ gcnt, const unsigned long long* __restrict__ pairs,
    int* __restrict__ row_start, int* __restrict__ row_end, int* __restrict__ eidx,
    u16* __restrict__ ew,
    const float* __restrict__ alpha_s, const float* __restrict__ alpha_d,
    const float* __restrict__ x, const u16* __restrict__ WT,
    u16* __restrict__ h)
{
    const int bid = blockIdx.x;
    const int t = threadIdx.x;
    if (bid < NMETA * NBUCK) {
        // ---- csrB: scan (4-aligned rows) + place + inline ew (transposed layout) ----
        const int m = bid / NBUCK, b = bid % NBUCK;
        __shared__ int cnt[512];
        __shared__ int off[512];
        __shared__ int wsum[4];
        int nb = gcnt[m * NBUCK + b]; if (nb > BCAP) nb = BCAP;
        const int base = (m * NBUCK + b) * BCAP;
        cnt[t] = 0; cnt[t + 256] = 0;
        __syncthreads();
        for (int e = t; e < nb; e += 256) {
            int dl = (int)(pairs[(size_t)base + e] >> 32);
            atomicAdd(&cnt[dl], 1);
        }
        __syncthreads();
        int c0 = cnt[2 * t], c1 = cnt[2 * t + 1];
        int v0p = (c0 + 3) & ~3, v1p = (c1 + 3) & ~3;   // pad rows to 4-slot alignment
        int s = v0p + v1p;
        int lane = t & 63, wv = t >> 6;
        int incl = s;
        #pragma unroll
        for (int o = 1; o < 64; o <<= 1) {
            int u = __shfl_up(incl, o);
            if (lane >= o) incl += u;
        }
        if (lane == 63) wsum[wv] = incl;
        __syncthreads();
        int woff = 0;
        for (int i = 0; i < wv; ++i) woff += wsum[i];
        int ex = woff + incl - s;
        off[2 * t] = ex;
        off[2 * t + 1] = ex + v0p;
        __syncthreads();
        const int node0 = b << SPAN_SHIFT;
        for (int i = t; i < 512; i += 256) {
            int n = node0 + i;
            if (n < N_NODES) {
                int st = base + off[i];
                row_start[m * N_NODES + n] = st;
                row_end[m * N_NODES + n]   = st + cnt[i];
            }
        }
        __syncthreads();
        const float* as_m = alpha_s + (size_t)m * N_NODES * 4;
        const float* ad_m = alpha_d + (size_t)m * N_NODES * 4;
        for (int e = t; e < nb; e += 256) {
            unsigned long long p = pairs[(size_t)base + e];
            int dl = (int)(p >> 32);
            int src128 = (int)(unsigned)p;
            int pos = atomicAdd(&off[dl], 1);
            int slot = base + pos;
            if (pos >= BCAP) continue;              // capacity guard (should not trigger)
            eidx[slot] = src128 * 2;                // byte offset of h row
            f32x4 as4 = *(const f32x4*)(as_m + (src128 >> 5));
            f32x4 ad4 = *(const f32x4*)(ad_m + (size_t)(node0 + dl) * 4);
            u16* ewp = ew + (size_t)(slot >> 2) * 16 + (slot & 3);
            #pragma unroll
            for (int k = 0; k < 4; ++k) {
                float pre = as4[k] + ad4[k];
                pre = fmaxf(pre, 0.2f * pre);
                ewp[k * 4] = f2bf(exp2f(pre));
            }
        }
        return;
    }
    // ---- gemm_h (pure; alphas handled in build1) ----
    const int g = bid - NMETA * NBUCK;
    const int bx = g % NABLK, m = g / NABLK;
    const int wv = t >> 6, lane = t & 63;
    const int row0 = (bx * 4 + wv) * 16;
    if (row0 >= N_NODES) return;
    const int lhi = lane >> 4, llo = lane & 15;
    const float* xrow = x + (size_t)(row0 + llo) * 128 + lhi * 8;
    bf16x8 a[4];
    #pragma unroll
    for (int ks = 0; ks < 4; ++ks) {
        float4 f0 = *(const float4*)(xrow + ks * 32);
        float4 f1 = *(const float4*)(xrow + ks * 32 + 4);
        bf16x8 av;
        av[0] = f2bf(f0.x); av[1] = f2bf(f0.y); av[2] = f2bf(f0.z); av[3] = f2bf(f0.w);
        av[4] = f2bf(f1.x); av[5] = f2bf(f1.y); av[6] = f2bf(f1.z); av[7] = f2bf(f1.w);
        a[ks] = av;
    }
    const u16* wbase = WT + (size_t)m * 16384 + (size_t)llo * 128 + lhi * 8;
    u16* hm = h + ((size_t)m * N_NODES + row0) * 128;
    #pragma unroll
    for (int cf = 0; cf < 8; ++cf) {
        f32x4 acc = {0.f, 0.f, 0.f, 0.f};
        const u16* wp = wbase + cf * 16 * 128;
        #pragma unroll
        for (int ks = 0; ks < 4; ++ks) {
            bf16x8 bb = *(const bf16x8*)(wp + ks * 32);
            acc = __builtin_amdgcn_mfma_f32_16x16x32_bf16(a[ks], bb, acc, 0, 0, 0);
        }
        const int col = cf * 16 + llo;
        #pragma unroll
        for (int r = 0; r < 4; ++r)
            hm[(size_t)(lhi * 4 + r) * 128 + col] = f2bf(acc[r]);
    }
}

// ---- K2: gather (aligned 4-slot groups, transposed ew) + softmax + bias + LN + ELU ----
__global__ __launch_bounds__(256) void k_gather(
    const int* __restrict__ row_start, const int* __restrict__ row_end,
    const int* __restrict__ eidx, const u16* __restrict__ ew,
    const float* __restrict__ alpha_s, const float* __restrict__ alpha_d,
    const u16* __restrict__ h,
    const float* __restrict__ bias, const float* __restrict__ gamma,
    const float* __restrict__ lbeta,
    u16* __restrict__ z)                 // [N, M, 128] bf16
{
    long long w = ((long long)blockIdx.x * blockDim.x + threadIdx.x) >> 6;
    if (w >= (long long)LTOT) return;
    int m = (int)(w / N_NODES), n = (int)(w % N_NODES);
    int lane = threadIdx.x & 63, hh = lane >> 4;
    const char* h_m = (const char*)(h + (size_t)m * N_NODES * 128);
    const char* ewb = (const char*)ew;
    const int lb = lane * 4;
    // self loop (alphas pre-scaled by LOG2E)
    const float* as_m = alpha_s + (size_t)m * N_NODES * 4;
    const float* ad_m = alpha_d + (size_t)m * N_NODES * 4;
    float pre = as_m[n * 4 + hh] + ad_m[n * 4 + hh];
    pre = fmaxf(pre, 0.2f * pre);
    float ev = exp2f(pre);
    float esum = ev;
    ushort2 hv = *(const ushort2*)(h_m + (size_t)n * 256 + lb);
    float acc0 = ev * bf2f(hv.x), acc1 = ev * bf2f(hv.y);
    int p = row_start[m * N_NODES + n];            // 4-aligned
    const int end = row_end[m * N_NODES + n];
    for (; p + 3 < end; p += 4) {
        int4 o4 = *(const int4*)(eidx + p);
        uint2 ewv = *(const uint2*)(ewb + (size_t)(p + hh) * 8);
        float e1 = u2f(ewv.x << 16), e2 = u2f(ewv.x & 0xffff0000u);
        float e3 = u2f(ewv.y << 16), e4 = u2f(ewv.y & 0xffff0000u);
        ushort2 h1 = *(const ushort2*)(h_m + o4.x + lb);
        ushort2 h2 = *(const ushort2*)(h_m + o4.y + lb);
        ushort2 h3 = *(const ushort2*)(h_m + o4.z + lb);
        ushort2 h4 = *(const ushort2*)(h_m + o4.w + lb);
        esum += (e1 + e2) + (e3 + e4);
        acc0 += e1 * bf2f(h1.x) + e2 * bf2f(h2.x) + e3 * bf2f(h3.x) + e4 * bf2f(h4.x);
        acc1 += e1 * bf2f(h1.y) + e2 * bf2f(h2.y) + e3 * bf2f(h3.y) + e4 * bf2f(h4.y);
    }
    for (; p < end; ++p) {
        int o1 = eidx[p];
        float e1 = bf2f(*(const u16*)(ewb + (size_t)((p & ~3) + hh) * 8 + (p & 3) * 2));
        ushort2 h1 = *(const ushort2*)(h_m + o1 + lb);
        esum += e1;
        acc0 += e1 * bf2f(h1.x);
        acc1 += e1 * bf2f(h1.y);
    }
    float rinv = 1.f / (esum + 1e-16f);
    float v0 = acc0 * rinv + bias[m * 128 + lane * 2];
    float v1 = acc1 * rinv + bias[m * 128 + lane * 2 + 1];
    float s1 = v0 + v1, s2 = v0 * v0 + v1 * v1;
    #pragma unroll
    for (int o = 32; o >= 1; o >>= 1) { s1 += __shfl_xor(s1, o); s2 += __shfl_xor(s2, o); }
    float mu = s1 * (1.f / 128.f);
    float var = s2 * (1.f / 128.f) - mu * mu;
    float rs = rsqrtf(var + 1e-5f);
    float o0 = (v0 - mu) * rs * gamma[lane * 2]     + lbeta[lane * 2];
    float o1 = (v1 - mu) * rs * gamma[lane * 2 + 1] + lbeta[lane * 2 + 1];
    o0 = o0 > 0.f ? o0 : (__expf(o0) - 1.f);
    o1 = o1 > 0.f ? o1 : (__expf(o1) - 1.f);
    ushort2 outv; outv.x = f2bf(o0); outv.y = f2bf(o1);
    *(ushort2*)(z + ((size_t)n * NMETA + m) * 128 + lane * 2) = outv;
}

// ---- K4: semantic scores via MFMA ----
__global__ __launch_bounds__(256) void k_sem(
    const u16* __restrict__ z, const u16* __restrict__ W1T,
    const float* __restrict__ b1, const float* __restrict__ W2,
    float* __restrict__ wpart)
{
    __shared__ float part[NMETA];
    const int t = threadIdx.x;
    if (t < NMETA) part[t] = 0.f;
    __syncthreads();
    const int wv = t >> 6, lane = t & 63;
    const int row0 = (blockIdx.x * 4 + wv) * 16;
    if (row0 < LTOT) {
        const int lhi = lane >> 4, llo = lane & 15;
        const u16* zrow = z + (size_t)(row0 + llo) * 128 + lhi * 8;
        bf16x8 a[4];
        #pragma unroll
        for (int ks = 0; ks < 4; ++ks) a[ks] = *(const bf16x8*)(zrow + ks * 32);
        const u16* wb = W1T + (size_t)llo * 128 + lhi * 8;
        float rowacc[4] = {0.f, 0.f, 0.f, 0.f};
        #pragma unroll
        for (int cf = 0; cf < 8; ++cf) {
            f32x4 acc = {0.f, 0.f, 0.f, 0.f};
            const u16* wp = wb + cf * 16 * 128;
            #pragma unroll
            for (int ks = 0; ks < 4; ++ks) {
                bf16x8 bb = *(const bf16x8*)(wp + ks * 32);
                acc = __builtin_amdgcn_mfma_f32_16x16x32_bf16(a[ks], bb, acc, 0, 0, 0);
            }
            int col = cf * 16 + llo;
            float b1v = b1[col], w2v = W2[col];
            #pragma unroll
            for (int r = 0; r < 4; ++r)
                rowacc[r] += tanhf(acc[r] + b1v) * w2v;
        }
        #pragma unroll
        for (int o = 1; o <= 8; o <<= 1) {
            #pragma unroll
            for (int r = 0; r < 4; ++r) rowacc[r] += __shfl_xor(rowacc[r], o);
        }
        if (llo == 0) {
            #pragma unroll
            for (int r = 0; r < 4; ++r)
                atomicAdd(&part[(row0 + lhi * 4 + r) % NMETA], rowacc[r]);
        }
    }
    __syncthreads();
    if (t < NMETA) atomicAdd(&wpart[t], part[t]);
}

// ---- K5 ----
__global__ void k_beta(const float* __restrict__ wpart, float* __restrict__ betab,
                       float* __restrict__ attout)
{
    if (threadIdx.x == 0 && blockIdx.x == 0) {
        float w0 = wpart[0] * (1.f / N_NODES);
        float w1 = wpart[1] * (1.f / N_NODES);
        float w2 = wpart[2] * (1.f / N_NODES);
        float mx = fmaxf(w0, fmaxf(w1, w2));
        float e0 = __expf(w0 - mx), e1 = __expf(w1 - mx), e2 = __expf(w2 - mx);
        float s = 1.f / (e0 + e1 + e2);
        float b0 = e0 * s, b1 = e1 * s, b2 = e2 * s;
        betab[0] = b0; betab[1] = b1; betab[2] = b2;
        attout[0] = b0; attout[1] = b1; attout[2] = b2;
    }
}

// ---- K6 ----
__global__ __launch_bounds__(256) void k_combine(
    const u16* __restrict__ z, const float* __restrict__ betab,
    float* __restrict__ out)
{
    int idx = blockIdx.x * blockDim.x + threadIdx.x;
    if (idx >= N_NODES * 64) return;
    int n = idx >> 6, c2 = (idx & 63) * 2;
    float b0 = betab[0], b1 = betab[1], b2 = betab[2];
    const u16* zp = z + (size_t)n * NMETA * 128 + c2;
    ushort2 a0 = *(const ushort2*)(zp);
    ushort2 a1 = *(const ushort2*)(zp + 128);
    ushort2 a2 = *(const ushort2*)(zp + 256);
    float2 ov;
    ov.x = b0 * bf2f(a0.x) + b1 * bf2f(a1.x) + b2 * bf2f(a2.x);
    ov.y = b0 * bf2f(a0.y) + b1 * bf2f(a1.y) + b2 * bf2f(a2.y);
    *(float2*)(out + (size_t)n * 128 + c2) = ov;
}

extern "C" void kernel_launch(void* const* d_in, const int* in_sizes, int n_in,
                              void* d_out, int out_size, void* d_ws, size_t ws_size,
                              hipStream_t stream) {
    const float* x       = (const float*)d_in[0];
    const int*   ei      = (const int*)d_in[1];
    const float* W       = (const float*)d_in[2];
    const float* att_src = (const float*)d_in[3];
    const float* att_dst = (const float*)d_in[4];
    const float* bias    = (const float*)d_in[5];
    const float* gamma   = (const float*)d_in[6];
    const float* lbeta   = (const float*)d_in[7];
    const float* W1      = (const float*)d_in[8];
    const float* b1      = (const float*)d_in[9];
    const float* W2      = (const float*)d_in[10];

    char* ws = (char*)d_ws;
    size_t off = 0;
    int* gcnt    = (int*)(ws + off);  off += sizeof(int) * 512;
    float* wpart = (float*)(ws + off);
    float* betab = wpart + 8;         off += 64;
    const size_t zero_bytes = off;
    off = (off + 255) & ~(size_t)255;
    int* row_start = (int*)(ws + off); off += sizeof(int) * 150016;
    int* row_end   = (int*)(ws + off); off += sizeof(int) * 150016;
    u16* h      = (u16*)(ws + off);    off += sizeof(u16) * (size_t)NMETA * N_NODES * 128;
    float* alpha_s = (float*)(ws + off); off += sizeof(float) * (size_t)LTOT * 4;
    float* alpha_d = (float*)(ws + off); off += sizeof(float) * (size_t)LTOT * 4;
    u16* WT     = (u16*)(ws + off);    off += sizeof(u16) * (size_t)NMETA * 128 * 128;
    u16* W1T    = (u16*)(ws + off);    off += sizeof(u16) * (size_t)128 * 128;
    int* eidx   = (int*)(ws + off);    off += sizeof(int) * (size_t)NMETA * NBUCK * BCAP;
    u16* ew     = (u16*)(ws + off);    off += sizeof(u16) * (size_t)NMETA * NBUCK * BCAP * 4;
    // union region (disjoint lifetimes): pairs (build1->build2), z (gather->end)
    unsigned long long* pairs = (unsigned long long*)(ws + off);
    u16* z = (u16*)(ws + off);
    off += sizeof(u16) * (size_t)N_NODES * NMETA * 128;                  // 38.4 MB
    if (ws_size < off) return;  // ~112 MB needed; loud failure if undersized

    hipMemsetAsync(d_ws, 0, zero_bytes, stream);

    // build1: csrA (441) || prep_w (256) || alpha (782)
    k_build1<<<dim3(NMETA * NCHUNK + 256 + NABLK), 256, 0, stream>>>(
        ei, gcnt, pairs, W, W1, WT, W1T, x, att_src, att_dst, alpha_s, alpha_d);
    // build2: csrB+ew (294) || gemm_h (2346)
    k_build2<<<dim3(NMETA * NBUCK + NABLK * NMETA), 256, 0, stream>>>(
        gcnt, pairs, row_start, row_end, eidx, ew, alpha_s, alpha_d, x, WT, h);
    k_gather<<<dim3((LTOT + 3) / 4), 256, 0, stream>>>(row_start, row_end, eidx, ew,
                                                       alpha_s, alpha_d, h,
                                                       bias, gamma, lbeta, z);
    k_sem<<<dim3((LTOT / 16 + 3) / 4), 256, 0, stream>>>(z, W1T, b1, W2, wpart);
    k_beta<<<1, 64, 0, stream>>>(wpart, betab, (float*)d_out + (size_t)N_NODES * 128);
    k_combine<<<dim3((N_NODES * 64 + 255) / 256), 256, 0, stream>>>(z, betab, (float*)d_out);
}

// Round 12
// 279.819 us; speedup vs baseline: 1.4185x; 1.4185x over previous
//
#include <hip/hip_runtime.h>
#include <hip/hip_bf16.h>

#define N_NODES 50000
#define N_EDGES 600000
#define NMETA   3
#define LTOT (NMETA * N_NODES)          // 150000
#define SPAN_SHIFT 9
#define NBUCK 98                         // ceil(50000 / 512)
#define BCAP 8192
#define NCHUNK 147                       // ceil(600000 / 4096)
#define NABLK 782                        // ceil(50000 / 64)
#define NSLOT (NMETA * NBUCK * BCAP)     // 2408448
#define LOG2E 1.4426950408889634f

typedef unsigned short u16;
typedef short bf16x8 __attribute__((ext_vector_type(8)));
typedef float f32x4 __attribute__((ext_vector_type(4)));

__device__ __forceinline__ float bf2f(u16 v) {
    union { unsigned int u; float f; } x; x.u = ((unsigned int)v) << 16; return x.f;
}
__device__ __forceinline__ float u2f(unsigned int u) {
    union { unsigned int u; float f; } x; x.u = u; return x.f;
}
__device__ __forceinline__ u16 f2bf(float f) {
    return __hip_bfloat16_raw(__float2bfloat16(f)).x;
}

// ---- build1: csrA (0..440) || prep_w (441..696) ----
__global__ __launch_bounds__(256) void k_build1(
    const int* __restrict__ ei, int* __restrict__ gcnt,
    unsigned long long* __restrict__ pairs,
    const float* __restrict__ W, const float* __restrict__ W1,
    u16* __restrict__ WT, u16* __restrict__ W1T)
{
    const int bid = blockIdx.x;
    const int t = threadIdx.x;
    if (bid >= NMETA * NCHUNK) {
        int idx = (bid - NMETA * NCHUNK) * 256 + t;
        if (idx < NMETA * 16384) {
            int m = idx >> 14, r = idx & 16383;
            int col = r >> 7, k = r & 127;
            WT[idx] = f2bf(W[(m << 14) + k * 128 + col]);
        } else {
            int r = idx - NMETA * 16384;
            int col = r >> 7, k = r & 127;
            W1T[r] = f2bf(W1[k * 128 + col]);
        }
        return;
    }
    const int m = bid / NCHUNK;
    const int e0 = (bid % NCHUNK) * 4096;
    __shared__ int cnt[NBUCK];
    __shared__ int gbase[NBUCK];
    if (t < NBUCK) cnt[t] = 0;
    __syncthreads();
    const int* srcp = ei + (size_t)m * 2 * N_EDGES;
    const int* dstp = srcp + N_EDGES;
    int sa[16], da[16], sl[16];
    #pragma unroll
    for (int j = 0; j < 16; ++j) {
        int e = e0 + j * 256 + t;
        if (e < N_EDGES) {
            int s = srcp[e], d = dstp[e];
            if ((unsigned)s >= N_NODES) s = 0;
            if ((unsigned)d >= N_NODES) d = 0;
            sa[j] = s; da[j] = d;
            sl[j] = atomicAdd(&cnt[d >> SPAN_SHIFT], 1);
        } else sl[j] = -1;
    }
    __syncthreads();
    if (t < NBUCK) gbase[t] = atomicAdd(&gcnt[m * NBUCK + t], cnt[t]);
    __syncthreads();
    #pragma unroll
    for (int j = 0; j < 16; ++j) {
        if (sl[j] < 0) continue;
        int b = da[j] >> SPAN_SHIFT;
        int pos = gbase[b] + sl[j];
        if (pos < BCAP)
            pairs[(size_t)(m * NBUCK + b) * BCAP + pos] =
                ((unsigned long long)(da[j] & 511) << 32) | (unsigned)(sa[j] * 128);
    }
}

// ---- build2: csrB (0..293, 4-aligned rows + sentinels + ptot) || gemm_h+alpha (rest) ----
__global__ __launch_bounds__(256) void k_build2(
    const int* __restrict__ gcnt, const unsigned long long* __restrict__ pairs,
    int* __restrict__ row_start, int* __restrict__ row_end, int* __restrict__ eidx,
    int* __restrict__ ptot,
    const float* __restrict__ x, const u16* __restrict__ WT,
    const float* __restrict__ att_src, const float* __restrict__ att_dst,
    u16* __restrict__ h, float* __restrict__ alpha_s, float* __restrict__ alpha_d)
{
    const int bid = blockIdx.x;
    const int t = threadIdx.x;
    if (bid < NMETA * NBUCK) {
        // ---- csrB: scan (4-aligned rows) + sentinel padding + place (packed) ----
        const int m = bid / NBUCK, b = bid % NBUCK;
        __shared__ int cnt[512];
        __shared__ int off[512];
        __shared__ int wsum[4];
        int nb = gcnt[m * NBUCK + b]; if (nb > BCAP) nb = BCAP;
        const int base = (m * NBUCK + b) * BCAP;
        cnt[t] = 0; cnt[t + 256] = 0;
        __syncthreads();
        for (int e = t; e < nb; e += 256) {
            int dl = (int)(pairs[(size_t)base + e] >> 32);
            atomicAdd(&cnt[dl], 1);
        }
        __syncthreads();
        int c0 = cnt[2 * t], c1 = cnt[2 * t + 1];
        int v0p = (c0 + 3) & ~3, v1p = (c1 + 3) & ~3;
        int s = v0p + v1p;
        int lane = t & 63, wv = t >> 6;
        int incl = s;
        #pragma unroll
        for (int o = 1; o < 64; o <<= 1) {
            int u = __shfl_up(incl, o);
            if (lane >= o) incl += u;
        }
        if (lane == 63) wsum[wv] = incl;
        __syncthreads();
        int woff = 0;
        for (int i = 0; i < wv; ++i) woff += wsum[i];
        int ex = woff + incl - s;
        off[2 * t] = ex;
        off[2 * t + 1] = ex + v0p;
        if (t == 255) {
            int tot = ex + v0p + v1p;
            ptot[m * NBUCK + b] = tot < BCAP ? tot : BCAP;
        }
        // sentinel-fill padding slots (positions [st+c, st+pad) of each row)
        for (int q = ex + c0; q < ex + v0p && q < BCAP; ++q) eidx[base + q] = 0;
        for (int q = ex + v0p + c1; q < ex + v0p + v1p && q < BCAP; ++q) eidx[base + q] = 0;
        __syncthreads();
        const int node0 = b << SPAN_SHIFT;
        for (int i = t; i < 512; i += 256) {
            int n = node0 + i;
            if (n < N_NODES) {
                int st = base + off[i];
                row_start[m * N_NODES + n] = st;
                row_end[m * N_NODES + n]   = st + cnt[i];
            }
        }
        __syncthreads();
        for (int e = t; e < nb; e += 256) {
            unsigned long long p = pairs[(size_t)base + e];
            int dl = (int)(p >> 32);
            int pos = atomicAdd(&off[dl], 1);
            if (pos >= BCAP) continue;
            eidx[base + pos] = (dl << 23) | (int)(unsigned)p;   // packed; k_ew unpacks
        }
        return;
    }
    // ---- gemm_h + fused alphas (pre-scaled by LOG2E) ----
    const int g = bid - NMETA * NBUCK;
    const int bx = g % NABLK, m = g / NABLK;
    const int wv = t >> 6, lane = t & 63;
    const int row0 = (bx * 4 + wv) * 16;
    if (row0 >= N_NODES) return;
    const int lhi = lane >> 4, llo = lane & 15;
    const float* xrow = x + (size_t)(row0 + llo) * 128 + lhi * 8;
    bf16x8 a[4];
    #pragma unroll
    for (int ks = 0; ks < 4; ++ks) {
        float4 f0 = *(const float4*)(xrow + ks * 32);
        float4 f1 = *(const float4*)(xrow + ks * 32 + 4);
        bf16x8 av;
        av[0] = f2bf(f0.x); av[1] = f2bf(f0.y); av[2] = f2bf(f0.z); av[3] = f2bf(f0.w);
        av[4] = f2bf(f1.x); av[5] = f2bf(f1.y); av[6] = f2bf(f1.z); av[7] = f2bf(f1.w);
        a[ks] = av;
    }
    const u16* wbase = WT + (size_t)m * 16384 + (size_t)llo * 128 + lhi * 8;
    u16* hm = h + ((size_t)m * N_NODES + row0) * 128;
    float sp[4][4], dp[4][4];
    #pragma unroll
    for (int i = 0; i < 4; ++i)
        #pragma unroll
        for (int r = 0; r < 4; ++r) { sp[i][r] = 0.f; dp[i][r] = 0.f; }
    #pragma unroll
    for (int cf = 0; cf < 8; ++cf) {
        f32x4 acc = {0.f, 0.f, 0.f, 0.f};
        const u16* wp = wbase + cf * 16 * 128;
        #pragma unroll
        for (int ks = 0; ks < 4; ++ks) {
            bf16x8 bb = *(const bf16x8*)(wp + ks * 32);
            acc = __builtin_amdgcn_mfma_f32_16x16x32_bf16(a[ks], bb, acc, 0, 0, 0);
        }
        const int col = cf * 16 + llo;
        const int hh = cf >> 1;
        const float as = att_src[m * 128 + col];
        const float adv = att_dst[m * 128 + col];
        #pragma unroll
        for (int r = 0; r < 4; ++r) {
            hm[(size_t)(lhi * 4 + r) * 128 + col] = f2bf(acc[r]);
            sp[hh][r] += acc[r] * as;
            dp[hh][r] += acc[r] * adv;
        }
    }
    #pragma unroll
    for (int o = 1; o <= 8; o <<= 1) {
        #pragma unroll
        for (int i = 0; i < 4; ++i)
            #pragma unroll
            for (int r = 0; r < 4; ++r) {
                sp[i][r] += __shfl_xor(sp[i][r], o);
                dp[i][r] += __shfl_xor(dp[i][r], o);
            }
    }
    if (llo == 0) {
        #pragma unroll
        for (int r = 0; r < 4; ++r) {
            int n = row0 + lhi * 4 + r;
            f32x4 vs = {sp[0][r] * LOG2E, sp[1][r] * LOG2E, sp[2][r] * LOG2E, sp[3][r] * LOG2E};
            f32x4 vd = {dp[0][r] * LOG2E, dp[1][r] * LOG2E, dp[2][r] * LOG2E, dp[3][r] * LOG2E};
            *(f32x4*)(alpha_s + ((size_t)m * N_NODES + n) * 4) = vs;
            *(f32x4*)(alpha_d + ((size_t)m * N_NODES + n) * 4) = vd;
        }
    }
}

// ---- k_ew: grid-stride per-slot edge weights (transposed ew layout); clean eidx ----
__global__ __launch_bounds__(256) void k_ew(
    const int* __restrict__ ptot, int* __restrict__ eidx,
    const float* __restrict__ alpha_s, const float* __restrict__ alpha_d,
    u16* __restrict__ ew)
{
    for (int sidx = blockIdx.x * 256 + threadIdx.x; sidx < NSLOT; sidx += gridDim.x * 256) {
        const int bucket = sidx >> 13;              // / BCAP
        const int i = sidx & (BCAP - 1);
        if (i >= ptot[bucket]) continue;
        const int m = bucket / NBUCK, b = bucket % NBUCK;
        const int node0 = b << SPAN_SHIFT;
        int v = eidx[sidx];
        int src128 = v & 0x7FFFFF;
        int dl = (unsigned)v >> 23;
        const float* as_m = alpha_s + (size_t)m * N_NODES * 4;
        const float* ad_m = alpha_d + (size_t)m * N_NODES * 4;
        f32x4 as4 = *(const f32x4*)(as_m + (src128 >> 5));
        f32x4 ad4 = *(const f32x4*)(ad_m + (size_t)(node0 + dl) * 4);
        u16* ewp = ew + (size_t)(sidx >> 2) * 16 + (sidx & 3);
        #pragma unroll
        for (int k = 0; k < 4; ++k) {
            float pre = as4[k] + ad4[k];
            pre = fmaxf(pre, 0.2f * pre);
            ewp[k * 4] = f2bf(exp2f(pre));
        }
        eidx[sidx] = src128 * 2;                    // byte offset of h row
    }
}

// ---- K2: gather (int4 eidx, uint2 transposed ew) + softmax + bias + LN + ELU ----
__global__ __launch_bounds__(256) void k_gather(
    const int* __restrict__ row_start, const int* __restrict__ row_end,
    const int* __restrict__ eidx, const u16* __restrict__ ew,
    const float* __restrict__ alpha_s, const float* __restrict__ alpha_d,
    const u16* __restrict__ h,
    const float* __restrict__ bias, const float* __restrict__ gamma,
    const float* __restrict__ lbeta,
    u16* __restrict__ z)                 // [N, M, 128] bf16
{
    long long w = ((long long)blockIdx.x * blockDim.x + threadIdx.x) >> 6;
    if (w >= (long long)LTOT) return;
    int m = (int)(w / N_NODES), n = (int)(w % N_NODES);
    int lane = threadIdx.x & 63, hh = lane >> 4;
    const char* h_m = (const char*)(h + (size_t)m * N_NODES * 128);
    const char* ewb = (const char*)ew;
    const int lb = lane * 4;
    const float* as_m = alpha_s + (size_t)m * N_NODES * 4;
    const float* ad_m = alpha_d + (size_t)m * N_NODES * 4;
    float pre = as_m[n * 4 + hh] + ad_m[n * 4 + hh];
    pre = fmaxf(pre, 0.2f * pre);
    float ev = exp2f(pre);
    float esum = ev;
    ushort2 hv = *(const ushort2*)(h_m + (size_t)n * 256 + lb);
    float acc0 = ev * bf2f(hv.x), acc1 = ev * bf2f(hv.y);
    int p = row_start[m * N_NODES + n];            // 4-aligned
    const int end = row_end[m * N_NODES + n];
    for (; p + 3 < end; p += 4) {
        int4 o4 = *(const int4*)(eidx + p);
        uint2 ewv = *(const uint2*)(ewb + (size_t)(p + hh) * 8);
        float e1 = u2f(ewv.x << 16), e2 = u2f(ewv.x & 0xffff0000u);
        float e3 = u2f(ewv.y << 16), e4 = u2f(ewv.y & 0xffff0000u);
        ushort2 h1 = *(const ushort2*)(h_m + o4.x + lb);
        ushort2 h2 = *(const ushort2*)(h_m + o4.y + lb);
        ushort2 h3 = *(const ushort2*)(h_m + o4.z + lb);
        ushort2 h4 = *(const ushort2*)(h_m + o4.w + lb);
        esum += (e1 + e2) + (e3 + e4);
        acc0 += e1 * bf2f(h1.x) + e2 * bf2f(h2.x) + e3 * bf2f(h3.x) + e4 * bf2f(h4.x);
        acc1 += e1 * bf2f(h1.y) + e2 * bf2f(h2.y) + e3 * bf2f(h3.y) + e4 * bf2f(h4.y);
    }
    for (; p < end; ++p) {
        int o1 = eidx[p];
        float e1 = bf2f(*(const u16*)(ewb + (size_t)((p & ~3) + hh) * 8 + (p & 3) * 2));
        ushort2 h1 = *(const ushort2*)(h_m + o1 + lb);
        esum += e1;
        acc0 += e1 * bf2f(h1.x);
        acc1 += e1 * bf2f(h1.y);
    }
    float rinv = 1.f / (esum + 1e-16f);
    float v0 = acc0 * rinv + bias[m * 128 + lane * 2];
    float v1 = acc1 * rinv + bias[m * 128 + lane * 2 + 1];
    float s1 = v0 + v1, s2 = v0 * v0 + v1 * v1;
    #pragma unroll
    for (int o = 32; o >= 1; o >>= 1) { s1 += __shfl_xor(s1, o); s2 += __shfl_xor(s2, o); }
    float mu = s1 * (1.f / 128.f);
    float var = s2 * (1.f / 128.f) - mu * mu;
    float rs = rsqrtf(var + 1e-5f);
    float o0 = (v0 - mu) * rs * gamma[lane * 2]     + lbeta[lane * 2];
    float o1 = (v1 - mu) * rs * gamma[lane * 2 + 1] + lbeta[lane * 2 + 1];
    o0 = o0 > 0.f ? o0 : (__expf(o0) - 1.f);
    o1 = o1 > 0.f ? o1 : (__expf(o1) - 1.f);
    ushort2 outv; outv.x = f2bf(o0); outv.y = f2bf(o1);
    *(ushort2*)(z + ((size_t)n * NMETA + m) * 128 + lane * 2) = outv;
}

// ---- K4: semantic scores via MFMA ----
__global__ __launch_bounds__(256) void k_sem(
    const u16* __restrict__ z, const u16* __restrict__ W1T,
    const float* __restrict__ b1, const float* __restrict__ W2,
    float* __restrict__ wpart)
{
    __shared__ float part[NMETA];
    const int t = threadIdx.x;
    if (t < NMETA) part[t] = 0.f;
    __syncthreads();
    const int wv = t >> 6, lane = t & 63;
    const int row0 = (blockIdx.x * 4 + wv) * 16;
    if (row0 < LTOT) {
        const int lhi = lane >> 4, llo = lane & 15;
        const u16* zrow = z + (size_t)(row0 + llo) * 128 + lhi * 8;
        bf16x8 a[4];
        #pragma unroll
        for (int ks = 0; ks < 4; ++ks) a[ks] = *(const bf16x8*)(zrow + ks * 32);
        const u16* wb = W1T + (size_t)llo * 128 + lhi * 8;
        float rowacc[4] = {0.f, 0.f, 0.f, 0.f};
        #pragma unroll
        for (int cf = 0; cf < 8; ++cf) {
            f32x4 acc = {0.f, 0.f, 0.f, 0.f};
            const u16* wp = wb + cf * 16 * 128;
            #pragma unroll
            for (int ks = 0; ks < 4; ++ks) {
                bf16x8 bb = *(const bf16x8*)(wp + ks * 32);
                acc = __builtin_amdgcn_mfma_f32_16x16x32_bf16(a[ks], bb, acc, 0, 0, 0);
            }
            int col = cf * 16 + llo;
            float b1v = b1[col], w2v = W2[col];
            #pragma unroll
            for (int r = 0; r < 4; ++r)
                rowacc[r] += tanhf(acc[r] + b1v) * w2v;
        }
        #pragma unroll
        for (int o = 1; o <= 8; o <<= 1) {
            #pragma unroll
            for (int r = 0; r < 4; ++r) rowacc[r] += __shfl_xor(rowacc[r], o);
        }
        if (llo == 0) {
            #pragma unroll
            for (int r = 0; r < 4; ++r)
                atomicAdd(&part[(row0 + lhi * 4 + r) % NMETA], rowacc[r]);
        }
    }
    __syncthreads();
    if (t < NMETA) atomicAdd(&wpart[t], part[t]);
}

// ---- K5 ----
__global__ void k_beta(const float* __restrict__ wpart, float* __restrict__ betab,
                       float* __restrict__ attout)
{
    if (threadIdx.x == 0 && blockIdx.x == 0) {
        float w0 = wpart[0] * (1.f / N_NODES);
        float w1 = wpart[1] * (1.f / N_NODES);
        float w2 = wpart[2] * (1.f / N_NODES);
        float mx = fmaxf(w0, fmaxf(w1, w2));
        float e0 = __expf(w0 - mx), e1 = __expf(w1 - mx), e2 = __expf(w2 - mx);
        float s = 1.f / (e0 + e1 + e2);
        float b0 = e0 * s, b1 = e1 * s, b2 = e2 * s;
        betab[0] = b0; betab[1] = b1; betab[2] = b2;
        attout[0] = b0; attout[1] = b1; attout[2] = b2;
    }
}

// ---- K6 ----
__global__ __launch_bounds__(256) void k_combine(
    const u16* __restrict__ z, const float* __restrict__ betab,
    float* __restrict__ out)
{
    int idx = blockIdx.x * blockDim.x + threadIdx.x;
    if (idx >= N_NODES * 64) return;
    int n = idx >> 6, c2 = (idx & 63) * 2;
    float b0 = betab[0], b1 = betab[1], b2 = betab[2];
    const u16* zp = z + (size_t)n * NMETA * 128 + c2;
    ushort2 a0 = *(const ushort2*)(zp);
    ushort2 a1 = *(const ushort2*)(zp + 128);
    ushort2 a2 = *(const ushort2*)(zp + 256);
    float2 ov;
    ov.x = b0 * bf2f(a0.x) + b1 * bf2f(a1.x) + b2 * bf2f(a2.x);
    ov.y = b0 * bf2f(a0.y) + b1 * bf2f(a1.y) + b2 * bf2f(a2.y);
    *(float2*)(out + (size_t)n * 128 + c2) = ov;
}

extern "C" void kernel_launch(void* const* d_in, const int* in_sizes, int n_in,
                              void* d_out, int out_size, void* d_ws, size_t ws_size,
                              hipStream_t stream) {
    const float* x       = (const float*)d_in[0];
    const int*   ei      = (const int*)d_in[1];
    const float* W       = (const float*)d_in[2];
    const float* att_src = (const float*)d_in[3];
    const float* att_dst = (const float*)d_in[4];
    const float* bias    = (const float*)d_in[5];
    const float* gamma   = (const float*)d_in[6];
    const float* lbeta   = (const float*)d_in[7];
    const float* W1      = (const float*)d_in[8];
    const float* b1      = (const float*)d_in[9];
    const float* W2      = (const float*)d_in[10];

    char* ws = (char*)d_ws;
    size_t off = 0;
    int* gcnt    = (int*)(ws + off);  off += sizeof(int) * 512;
    int* ptot    = (int*)(ws + off);  off += sizeof(int) * 512;
    float* wpart = (float*)(ws + off);
    float* betab = wpart + 8;         off += 64;
    const size_t zero_bytes = off;
    off = (off + 255) & ~(size_t)255;
    int* row_start = (int*)(ws + off); off += sizeof(int) * 150016;
    int* row_end   = (int*)(ws + off); off += sizeof(int) * 150016;
    u16* h      = (u16*)(ws + off);    off += sizeof(u16) * (size_t)NMETA * N_NODES * 128;
    float* alpha_s = (float*)(ws + off); off += sizeof(float) * (size_t)LTOT * 4;
    float* alpha_d = (float*)(ws + off); off += sizeof(float) * (size_t)LTOT * 4;
    u16* WT     = (u16*)(ws + off);    off += sizeof(u16) * (size_t)NMETA * 128 * 128;
    u16* W1T    = (u16*)(ws + off);    off += sizeof(u16) * (size_t)128 * 128;
    int* eidx   = (int*)(ws + off);    off += sizeof(int) * (size_t)NSLOT;          // 9.6 MB
    u16* ew     = (u16*)(ws + off);    off += sizeof(u16) * (size_t)NSLOT * 4;      // 19.3 MB
    // union region (disjoint lifetimes): pairs (build1->build2), z (gather->end)
    unsigned long long* pairs = (unsigned long long*)(ws + off);
    u16* z = (u16*)(ws + off);
    off += sizeof(u16) * (size_t)N_NODES * NMETA * 128;                  // 38.4 MB
    if (ws_size < off) return;  // ~112 MB needed; loud failure if undersized

    hipMemsetAsync(d_ws, 0, zero_bytes, stream);

    // build1: csrA (441) || prep_w (256)
    k_build1<<<dim3(NMETA * NCHUNK + 256), 256, 0, stream>>>(ei, gcnt, pairs, W, W1, WT, W1T);
    // build2: csrB (294) || gemm_h+alpha (2346)
    k_build2<<<dim3(NMETA * NBUCK + NABLK * NMETA), 256, 0, stream>>>(
        gcnt, pairs, row_start, row_end, eidx, ptot,
        x, WT, att_src, att_dst, h, alpha_s, alpha_d);
    k_ew<<<dim3(2048), 256, 0, stream>>>(ptot, eidx, alpha_s, alpha_d, ew);
    k_gather<<<dim3((LTOT + 3) / 4), 256, 0, stream>>>(row_start, row_end, eidx, ew,
                                                       alpha_s, alpha_d, h,
                                                       bias, gamma, lbeta, z);
    k_sem<<<dim3((LTOT / 16 + 3) / 4), 256, 0, stream>>>(z, W1T, b1, W2, wpart);
    k_beta<<<1, 64, 0, stream>>>(wpart, betab, (float*)d_out + (size_t)N_NODES * 128);
    k_combine<<<dim3((N_NODES * 64 + 255) / 256), 256, 0, stream>>>(z, betab, (float*)d_out);
}